// Round 5
// baseline (115.775 us; speedup 1.0000x reference)
//
#include <hip/hip_runtime.h>
#include <math.h>

#define TPB 256
#define NCH 34             // radial channels

typedef float fx4 __attribute__((ext_vector_type(4)));
typedef float fx2 __attribute__((ext_vector_type(2)));

// Single kernel: per-pair SH (16 cols) + 34-channel hermite radial spline.
// One thread = one pair in the compute phase (results staged in LDS);
// block-coalesced dense nt stores afterwards. sv/sd (136 KB each) stay
// L2-resident; loads are fx2 (8B) row-pair gathers.
__global__ __launch_bounds__(TPB) void precompute_kernel(
    const float* __restrict__ pos,    // (N_ATOMS,3)
    const float* __restrict__ cells,  // (N_STRUCT,3,3)
    const int*   __restrict__ shifts, // (N,3)
    const int*   __restrict__ cidx,
    const int*   __restrict__ nidx,
    const int*   __restrict__ spair,
    const int*   __restrict__ cspec,
    const int*   __restrict__ nspec,
    const float* __restrict__ ls,     // (9,)
    const float* __restrict__ sv,     // (1001,34)
    const float* __restrict__ sd,     // (1001,34)
    float* __restrict__ outY,         // (N,16)
    float* __restrict__ outR,         // (N,34)
    int n)
{
    __shared__ float sY[TPB][18];     // stride 18: fx2-aligned, 4-way-max banks
    __shared__ float sW[TPB][4];      // hermite weights * gate (DELTA folded)
    __shared__ int   sI[TPB];         // idx*17 (fx2 row base into sv/sd)

    const int tid  = threadIdx.x;
    const int base = blockIdx.x * TPB;
    const int p    = base + tid;

    if (p < n) {
        const int ci = cidx[p], ni = nidx[p], sp = spair[p];
        const int cs = cspec[p], ns = nspec[p];
        const float f0 = (float)shifts[3*p];
        const float f1 = (float)shifts[3*p+1];
        const float f2 = (float)shifts[3*p+2];
        const float* cl = cells + sp * 9;

        float vx = pos[3*ni+0] - pos[3*ci+0] + f0*cl[0] + f1*cl[3] + f2*cl[6];
        float vy = pos[3*ni+1] - pos[3*ci+1] + f0*cl[1] + f1*cl[4] + f2*cl[7];
        float vz = pos[3*ni+2] - pos[3*ci+2] + f0*cl[2] + f1*cl[5] + f2*cl[8];

        const float rsq = vx*vx + vy*vy + vz*vz;
        const float r   = sqrtf(rsq);
        const float inv = 1.0f / r;
        const float x = vx*inv, y = vy*inv, z = vz*inv;
        const float x2 = x*x, y2 = y*y, z2 = z*z;

        // Real SH * sqrt(4pi), reference column order.
        sY[tid][0]  = 1.0f;
        sY[tid][1]  = 1.7320508075688772f * y;
        sY[tid][2]  = 1.7320508075688772f * z;
        sY[tid][3]  = 1.7320508075688772f * x;
        sY[tid][4]  = 3.872983346207417f  * x * y;
        sY[tid][5]  = 3.872983346207417f  * y * z;
        sY[tid][6]  = 1.118033988749895f  * (3.0f*z2 - 1.0f);
        sY[tid][7]  = 3.872983346207417f  * x * z;
        sY[tid][8]  = 1.9364916731037085f * (x2 - y2);
        sY[tid][9]  = 2.091650066335189f  * y * (3.0f*x2 - y2);
        sY[tid][10] = 10.246950765959598f * x * y * z;
        sY[tid][11] = 1.6201851746019651f * y * (5.0f*z2 - 1.0f);
        sY[tid][12] = 1.3228756555322954f * z * (5.0f*z2 - 3.0f);
        sY[tid][13] = 1.6201851746019651f * x * (5.0f*z2 - 1.0f);
        sY[tid][14] = 5.123475382979799f  * z * (x2 - y2);
        sY[tid][15] = 2.091650066335189f  * x * (x2 - 3.0f*y2);

        // Radial metadata.
        const float denom = 0.1f + __expf(ls[cs]) + __expf(ls[ns]);
        const float xx = r / denom;
        const bool  valid = xx < 10.0f;
        const float cx = valid ? xx : 5.0f;
        const float DELTA = 0.01f;
        int idx = (int)floorf(cx * 100.0f);
        idx = idx < 0 ? 0 : (idx > 999 ? 999 : idx);
        const float t  = (cx - (float)idx * DELTA) * 100.0f;
        const float t2 = t*t, t3 = t2*t;
        // cutoff exactly as reference (unclamped 1+cos beyond r_cut)
        const float cut = (r < 4.5f) ? 1.0f
                        : (1.0f + __cosf((r - 4.5f) * 6.2831853071795864f));
        const float g = valid ? cut : 0.0f;
        sW[tid][0] = ( 2.0f*t3 - 3.0f*t2 + 1.0f) * g;           // h00*g
        sW[tid][1] = (      t3 - 2.0f*t2 + t   ) * g * DELTA;   // h10*g*DELTA
        sW[tid][2] = (-2.0f*t3 + 3.0f*t2       ) * g;           // h01*g
        sW[tid][3] = (      t3 -      t2       ) * g * DELTA;   // h11*g*DELTA
        sI[tid] = idx * 17;          // fx2-row base: row idx starts at fx2 idx*17
    }
    __syncthreads();

    const int remain = n - base;
    const int nact   = remain >= TPB ? TPB : remain;

    // Y phase: dense fx2 nt stores. Block tile = nact*8 fx2 elements.
    {
        fx2* Yb = (fx2*)(outY + (size_t)base * 16);
        const int totY = nact * 8;
        #pragma unroll
        for (int j = 0; j < 8; ++j) {
            int e2 = j * TPB + tid;
            if (e2 < totY) {
                int pp = e2 >> 3, cc = (e2 & 7) * 2;
                fx2 o;
                o.x = sY[pp][cc];
                o.y = sY[pp][cc + 1];
                __builtin_nontemporal_store(o, Yb + e2);
            }
        }
    }

    // Radial phase: block tile = nact pairs x 17 fx2-channels.
    {
        const fx2* sv2 = (const fx2*)sv;
        const fx2* sd2 = (const fx2*)sd;
        const int tot = nact * 17;
        float* Rb = outR + (size_t)base * NCH;
        #pragma unroll
        for (int k = 0; k < 17; ++k) {
            int ef = k * TPB + tid;
            if (ef < tot) {
                int pp = ef / 17;
                int c2 = ef - pp * 17;          // fx2-channel, cc = 2*c2
                float w0 = sW[pp][0], w1 = sW[pp][1];
                float w2 = sW[pp][2], w3 = sW[pp][3];
                int o0 = sI[pp] + c2;           // fx2 index, row idx
                fx2 v0 = sv2[o0];
                fx2 d0 = sd2[o0];
                fx2 v1 = sv2[o0 + 17];          // row idx+1
                fx2 d1 = sd2[o0 + 17];
                fx2 o;
                o.x = w0*v0.x + w1*d0.x + w2*v1.x + w3*d1.x;
                o.y = w0*v0.y + w1*d0.y + w2*v1.y + w3*d1.y;
                float* dst = Rb + pp * NCH + 2 * c2;   // 8B-aligned (34 even)
                __builtin_nontemporal_store(o, (fx2*)dst);
            }
        }
    }
}

extern "C" void kernel_launch(void* const* d_in, const int* in_sizes, int n_in,
                              void* d_out, int out_size, void* d_ws, size_t ws_size,
                              hipStream_t stream) {
    const float* pos    = (const float*)d_in[0];
    const float* cells  = (const float*)d_in[1];
    const int*   shifts = (const int*)d_in[2];
    const int*   cidx   = (const int*)d_in[3];
    const int*   nidx   = (const int*)d_in[4];
    const int*   spair  = (const int*)d_in[5];
    const int*   cspec  = (const int*)d_in[6];
    const int*   nspec  = (const int*)d_in[7];
    const float* ls     = (const float*)d_in[8];
    const float* sv     = (const float*)d_in[9];
    const float* sd     = (const float*)d_in[10];

    const int n = in_sizes[3];              // N_PAIRS
    float* outY = (float*)d_out;            // (N,16)
    float* outR = outY + (size_t)n * 16;    // (N,34)

    const int grid = (n + TPB - 1) / TPB;
    hipLaunchKernelGGL(precompute_kernel, dim3(grid), dim3(TPB), 0, stream,
                       pos, cells, shifts, cidx, nidx, spair, cspec, nspec,
                       ls, sv, sd, outY, outR, n);
}

// Round 6
// 93.600 us; speedup vs baseline: 1.2369x; 1.2369x over previous
//
#include <hip/hip_runtime.h>
#include <math.h>

#define TPB 256
#define N_GRID_ROWS 1000   // spline segments (idx in [0,999])
#define NCH 34             // radial channels
#define T2_ELEMS (N_GRID_ROWS * NCH)
#define T2_BYTES (T2_ELEMS * 16)

typedef float fx4 __attribute__((ext_vector_type(4)));
typedef float fx2 __attribute__((ext_vector_type(2)));

// Prologue: fuse (sv[i][c], 0.01*sd[i][c], sv[i+1][c], 0.01*sd[i+1][c]) into
// one fx4 per (segment,channel). 544 KB -> L2-resident during main kernel.
// Radial inner loop then needs 2 fx4 loads per 2 output channels.
__global__ __launch_bounds__(TPB) void build_t2_kernel(
    const float* __restrict__ sv, const float* __restrict__ sd,
    fx4* __restrict__ T2)
{
    int e = blockIdx.x * TPB + threadIdx.x;
    if (e < T2_ELEMS) {
        fx4 v;
        v.x = sv[e];
        v.y = 0.01f * sd[e];
        v.z = sv[e + NCH];
        v.w = 0.01f * sd[e + NCH];
        T2[e] = v;
    }
}

__global__ __launch_bounds__(TPB) void precompute_kernel(
    const float* __restrict__ pos,    // (N_ATOMS,3)
    const float* __restrict__ cells,  // (N_STRUCT,3,3)
    const int*   __restrict__ shifts, // (N,3)
    const int*   __restrict__ cidx,
    const int*   __restrict__ nidx,
    const int*   __restrict__ spair,
    const int*   __restrict__ cspec,
    const int*   __restrict__ nspec,
    const float* __restrict__ ls,     // (9,)
    const fx4*   __restrict__ T2,     // fused spline table
    float* __restrict__ outY,         // (N,16)
    float* __restrict__ outR,         // (N,34)
    int n)
{
    __shared__ float sY[TPB][20];     // stride 20: rows 80B -> cc*16 is 16B-aligned
    __shared__ float sW[TPB][4];      // hermite weights * gate (DELTA folded in T2)
    __shared__ int   sI[TPB];         // idx*34 (row base in T2 elements)

    const int tid  = threadIdx.x;
    const int base = blockIdx.x * TPB;
    const int p    = base + tid;

    if (p < n) {
        const int ci = cidx[p], ni = nidx[p], sp = spair[p];
        const int cs = cspec[p], ns = nspec[p];
        const float f0 = (float)shifts[3*p];
        const float f1 = (float)shifts[3*p+1];
        const float f2 = (float)shifts[3*p+2];
        const float* cl = cells + sp * 9;

        float vx = pos[3*ni+0] - pos[3*ci+0] + f0*cl[0] + f1*cl[3] + f2*cl[6];
        float vy = pos[3*ni+1] - pos[3*ci+1] + f0*cl[1] + f1*cl[4] + f2*cl[7];
        float vz = pos[3*ni+2] - pos[3*ci+2] + f0*cl[2] + f1*cl[5] + f2*cl[8];

        const float rsq = vx*vx + vy*vy + vz*vz;
        const float r   = sqrtf(rsq);
        const float inv = 1.0f / r;
        const float x = vx*inv, y = vy*inv, z = vz*inv;
        const float x2 = x*x, y2 = y*y, z2 = z*z;

        // Real SH * sqrt(4pi), reference column order.
        sY[tid][0]  = 1.0f;
        sY[tid][1]  = 1.7320508075688772f * y;
        sY[tid][2]  = 1.7320508075688772f * z;
        sY[tid][3]  = 1.7320508075688772f * x;
        sY[tid][4]  = 3.872983346207417f  * x * y;
        sY[tid][5]  = 3.872983346207417f  * y * z;
        sY[tid][6]  = 1.118033988749895f  * (3.0f*z2 - 1.0f);
        sY[tid][7]  = 3.872983346207417f  * x * z;
        sY[tid][8]  = 1.9364916731037085f * (x2 - y2);
        sY[tid][9]  = 2.091650066335189f  * y * (3.0f*x2 - y2);
        sY[tid][10] = 10.246950765959598f * x * y * z;
        sY[tid][11] = 1.6201851746019651f * y * (5.0f*z2 - 1.0f);
        sY[tid][12] = 1.3228756555322954f * z * (5.0f*z2 - 3.0f);
        sY[tid][13] = 1.6201851746019651f * x * (5.0f*z2 - 1.0f);
        sY[tid][14] = 5.123475382979799f  * z * (x2 - y2);
        sY[tid][15] = 2.091650066335189f  * x * (x2 - 3.0f*y2);

        // Radial metadata.
        const float denom = 0.1f + __expf(ls[cs]) + __expf(ls[ns]);
        const float xx = r / denom;
        const bool  valid = xx < 10.0f;
        const float cx = valid ? xx : 5.0f;
        const float DELTA = 0.01f;
        int idx = (int)floorf(cx * 100.0f);
        idx = idx < 0 ? 0 : (idx > 999 ? 999 : idx);
        const float t  = (cx - (float)idx * DELTA) * 100.0f;
        const float t2 = t*t, t3 = t2*t;
        // cutoff exactly as reference (unclamped 1+cos beyond r_cut)
        const float cut = (r < 4.5f) ? 1.0f
                        : (1.0f + __cosf((r - 4.5f) * 6.2831853071795864f));
        const float g = valid ? cut : 0.0f;
        sW[tid][0] = ( 2.0f*t3 - 3.0f*t2 + 1.0f) * g;   // h00*g
        sW[tid][1] = (      t3 - 2.0f*t2 + t   ) * g;   // h10*g (DELTA in T2)
        sW[tid][2] = (-2.0f*t3 + 3.0f*t2       ) * g;   // h01*g
        sW[tid][3] = (      t3 -      t2       ) * g;   // h11*g
        sI[tid] = idx * NCH;
    }
    __syncthreads();

    const int remain = n - base;
    const int nact   = remain >= TPB ? TPB : remain;

    // Y phase: dense fx4 nt stores. Block tile = nact*4 fx4 elements.
    {
        fx4* Yb = (fx4*)(outY + (size_t)base * 16);
        const int totY = nact * 4;
        #pragma unroll
        for (int j = 0; j < 4; ++j) {
            int e4 = j * TPB + tid;
            if (e4 < totY) {
                int pp = e4 >> 2, cc = (e4 & 3) * 4;
                fx4 o = *(const fx4*)&sY[pp][cc];   // 16B-aligned (stride 20)
                __builtin_nontemporal_store(o, Yb + e4);
            }
        }
    }

    // Radial phase: block tile = nact pairs x 17 fx2-channels; 2 fx4 loads each.
    {
        const int tot = nact * 17;
        float* Rb = outR + (size_t)base * NCH;
        #pragma unroll
        for (int k = 0; k < 17; ++k) {
            int ef = k * TPB + tid;
            if (ef < tot) {
                int pp = ef / 17;
                int c2 = ef - pp * 17;          // fx2-channel, cc = 2*c2
                float w0 = sW[pp][0], w1 = sW[pp][1];
                float w2 = sW[pp][2], w3 = sW[pp][3];
                int off = sI[pp] + 2 * c2;
                fx4 a = T2[off];
                fx4 b = T2[off + 1];
                fx2 o;
                o.x = w0*a.x + w1*a.y + w2*a.z + w3*a.w;
                o.y = w0*b.x + w1*b.y + w2*b.z + w3*b.w;
                float* dst = Rb + pp * NCH + 2 * c2;   // 8B-aligned (34 even)
                __builtin_nontemporal_store(o, (fx2*)dst);
            }
        }
    }
}

extern "C" void kernel_launch(void* const* d_in, const int* in_sizes, int n_in,
                              void* d_out, int out_size, void* d_ws, size_t ws_size,
                              hipStream_t stream) {
    const float* pos    = (const float*)d_in[0];
    const float* cells  = (const float*)d_in[1];
    const int*   shifts = (const int*)d_in[2];
    const int*   cidx   = (const int*)d_in[3];
    const int*   nidx   = (const int*)d_in[4];
    const int*   spair  = (const int*)d_in[5];
    const int*   cspec  = (const int*)d_in[6];
    const int*   nspec  = (const int*)d_in[7];
    const float* ls     = (const float*)d_in[8];
    const float* sv     = (const float*)d_in[9];
    const float* sd     = (const float*)d_in[10];

    const int n = in_sizes[3];              // N_PAIRS
    float* outY = (float*)d_out;            // (N,16)
    float* outR = outY + (size_t)n * 16;    // (N,34)

    fx4* T2 = (fx4*)d_ws;                   // ws ample (>= 544 KB)
    const int gb = (T2_ELEMS + TPB - 1) / TPB;
    hipLaunchKernelGGL(build_t2_kernel, dim3(gb), dim3(TPB), 0, stream, sv, sd, T2);

    const int grid = (n + TPB - 1) / TPB;
    hipLaunchKernelGGL(precompute_kernel, dim3(grid), dim3(TPB), 0, stream,
                       pos, cells, shifts, cidx, nidx, spair, cspec, nspec,
                       ls, T2, outY, outR, n);
}